// Round 5
// baseline (1436.185 us; speedup 1.0000x reference)
//
#include <hip/hip_runtime.h>
#include <cfloat>

// Problem constants (match reference)
constexpr int Bn = 1024, Ln = 1024, Vn = 20, Dn = 128;
constexpr int NJ = 2 * Vn;      // 40 output columns
constexpr int RESYNC = 16;      // exact re-dot every RESYNC steps

// v mod 20 for 0 <= v <= ~1000 (magic multiply, exact in this range)
__device__ __forceinline__ int mod20(int v) { return v - 20 * ((v * 205) >> 12); }
__device__ __forceinline__ float max3f(float a, float b, float c) {
  return fmaxf(fmaxf(a, b), c);
}

// ---- X-macro lists: 40 NAMED f64 nets (loop-carried -> forced into VGPRs) ----
#define L40(M) M(0)M(1)M(2)M(3)M(4)M(5)M(6)M(7)M(8)M(9)M(10)M(11)M(12)M(13)M(14)M(15)M(16)M(17)M(18)M(19)M(20)M(21)M(22)M(23)M(24)M(25)M(26)M(27)M(28)M(29)M(30)M(31)M(32)M(33)M(34)M(35)M(36)M(37)M(38)M(39)
#define LA(M) M(0)M(1)M(2)M(3)M(4)M(5)M(6)M(7)M(8)M(9)M(10)M(11)M(12)M(13)M(14)M(15)M(16)M(17)M(18)M(19)
#define LB(M) M(20)M(21)M(22)M(23)M(24)M(25)M(26)M(27)M(28)M(29)M(30)M(31)M(32)M(33)M(34)M(35)M(36)M(37)M(38)M(39)
// double2 pair list: (pair index, even net, odd net)
#define LP(M) M(0,0,1)M(1,2,3)M(2,4,5)M(3,6,7)M(4,8,9)M(5,10,11)M(6,12,13)M(7,14,15)M(8,16,17)M(9,18,19)M(10,20,21)M(11,22,23)M(12,24,25)M(13,26,27)M(14,28,29)M(15,30,31)M(16,32,33)M(17,34,35)M(18,36,37)M(19,38,39)

__global__ __launch_bounds__(64, 1) void daf_chain(
    const float* __restrict__ x, const float* __restrict__ emb,
    const float* __restrict__ W, const float* __restrict__ bvec,
    float* __restrict__ out)
{
  __shared__ float  Ws[Dn * NJ];                 // 20480 B: W staged f32
  __shared__ float  embs[Vn * Dn];               // 10240 B
  __shared__ alignas(16) double EW[Vn * NJ];     //  6400 B: EW[k][j] = emb[k]·W[:,j]
  __shared__ alignas(16) double st64[Dn];        //  1024 B: f64 copy of f32 state
  __shared__ alignas(16) double nets40[NJ];      //   320 B: resync share buffer
  __shared__ unsigned char aidx[Ln];             //  1024 B: token index per step
  // total 39488 B -> 4 blocks/CU

  const int lane  = threadIdx.x;
  const int batch = blockIdx.x;

  // Resync ownership: lanes 0..19 own loc columns, 32..51 own scale columns.
  const bool active = (lane < Vn) || (lane >= 32 && lane < 32 + Vn);
  const int  jm     = (lane < 32) ? lane : (lane - 32 + Vn);
  const int  jc     = active ? jm : 0;

  // ---- Prologue: stage W, emb; extract token indices (coalesced float4) ----
  for (int i = lane; i < Dn * NJ; i += 64) Ws[i] = W[i];
  for (int i = lane; i < Vn * Dn; i += 64) embs[i] = emb[i];
  const float4* xb4 = (const float4*)(x + (size_t)batch * Ln * Vn);
  for (int i = lane; i < Ln * (Vn / 4); i += 64) {  // 5 float4 per row of 20
    const float4 v = xb4[i];
    const int row = i / 5, cb = (i % 5) * 4;
    if (v.x > 0.5f) aidx[row] = (unsigned char)(cb + 0);
    if (v.y > 0.5f) aidx[row] = (unsigned char)(cb + 1);
    if (v.z > 0.5f) aidx[row] = (unsigned char)(cb + 2);
    if (v.w > 0.5f) aidx[row] = (unsigned char)(cb + 3);
  }
  __syncthreads();

  // ---- EW[k][j] = sum_d emb[k][d] * W[d][j], f64 ----
  for (int p = lane; p < Vn * NJ; p += 64) {
    const int k = p / NJ, j = p - k * NJ;
    double acc = 0.0;
#pragma unroll 4
    for (int d = 0; d < Dn; ++d)
      acc = __builtin_fma((double)embs[k * Dn + d], (double)Ws[d * NJ + j], acc);
    EW[p] = acc;
  }
  __syncthreads();

  const double bj = (double)bvec[jc];

  // All 40 nets replicated in every lane; init = b (exact state-0 nets).
#define NINIT(i) double n##i = (double)bvec[i];
  L40(NINIT)

  float s32a = 0.0f, s32b = 0.0f;   // bit-exact f32 state walk (d=lane, lane+64)
  float* outb = out + (size_t)batch * Ln * Vn;
  const double2* st2 = (const double2*)st64;
  const float*   Wsc = Ws + jc;

  for (int t = 0; t < Ln; ++t) {
    const int a = (int)aidx[t];     // uniform LDS read, issued early

    // ---- f32 keys (matches reference's f32 argmax domain) ----
#define KCVT(i) const float k##i = (float)n##i;
    L40(KCVT)

    // ---- argmax half A (loc, j=0..19): max3 tree + first-equal scan ----
    const float mxA = max3f(
        max3f(max3f(k0, k1, k2),  max3f(k3, k4, k5),   max3f(k6, k7, k8)),
        max3f(max3f(k9, k10, k11), max3f(k12, k13, k14), max3f(k15, k16, k17)),
        fmaxf(k18, k19));
    unsigned bA = 0u;
#define BITA(i) bA |= (k##i == mxA) ? (1u << (i)) : 0u;
    LA(BITA)
    // ---- argmax half B (scale, j=20..39) ----
    const float mxB = max3f(
        max3f(max3f(k20, k21, k22), max3f(k23, k24, k25), max3f(k26, k27, k28)),
        max3f(max3f(k29, k30, k31), max3f(k32, k33, k34), max3f(k35, k36, k37)),
        fmaxf(k38, k39));
    unsigned bB = 0u;
#define BITB(i) bB |= (k##i == mxB) ? (1u << ((i) - 20)) : 0u;
    LB(BITB)

    const int loc   = __builtin_amdgcn_readfirstlane(__ffs(bA) - 1);
    const int scale = __builtin_amdgcn_readfirstlane(__ffs(bB) - 1);
    const int as    = __builtin_amdgcn_readfirstlane(a);

    // out_idx = (inv20(scale) * ((as - loc) mod 20)) mod 20   (scalar math)
    int r = as - loc; r += (r >> 31) & Vn;
    const int s  = scale;
    const int s2 = mod20(s * s);
    const int s4 = mod20(s2 * s2);
    const int s6 = mod20(s4 * s2);
    int inv = mod20(s6 * s);                 // s^7 mod 20 (= s^-1 for coprime s)
    const bool cop = ((s & 1) != 0) && ((s - 5 * ((s * 205) >> 10)) != 0);
    inv = cop ? inv : 0;                     // non-coprime -> INV_P row = e_0
    const int oidx = mod20(inv * r);

    // One-hot output row (80B store, fire-and-forget)
    if (lane < Vn) outb[(size_t)t * Vn + lane] = (lane == oidx) ? 1.0f : 0.0f;

    // Exact f32 state walk (bit-reproducible)
    s32a += embs[oidx * Dn + lane];
    s32b += embs[oidx * Dn + lane + 64];

    if (((t + 1) & (RESYNC - 1)) == 0 && (t + 1) < Ln) {
      // ---- Resync: nets = b + f64 dot of exact f32 state (proven numerics),
      //      distributed one column per lane, shared via 320B LDS broadcast.
      st64[lane]      = (double)s32a;
      st64[lane + 64] = (double)s32b;
      double acc0 = 0.0, acc1 = 0.0, acc2 = 0.0, acc3 = 0.0;
#pragma unroll
      for (int d = 0; d < Dn; d += 4) {
        const double2 sA = st2[d >> 1];
        const double2 sB = st2[(d >> 1) + 1];
        acc0 = __builtin_fma(sA.x, (double)Wsc[(d + 0) * NJ], acc0);
        acc1 = __builtin_fma(sA.y, (double)Wsc[(d + 1) * NJ], acc1);
        acc2 = __builtin_fma(sB.x, (double)Wsc[(d + 2) * NJ], acc2);
        acc3 = __builtin_fma(sB.y, (double)Wsc[(d + 3) * NJ], acc3);
      }
      if (active) nets40[jm] = ((acc0 + acc1) + (acc2 + acc3)) + bj;
      const double2* nr = (const double2*)nets40;
#define NLOAD(i, a_, b_) { const double2 q = nr[i]; n##a_ = q.x; n##b_ = q.y; }
      LP(NLOAD)
    } else {
      // ---- Incremental: nets += EW[oidx][:], 20 broadcast b128 reads ----
      const double2* er = (const double2*)(EW + oidx * NJ);
#define NADD(i, a_, b_) { const double2 q = er[i]; n##a_ += q.x; n##b_ += q.y; }
      LP(NADD)
    }
  }
}

extern "C" void kernel_launch(void* const* d_in, const int* in_sizes, int n_in,
                              void* d_out, int out_size, void* d_ws, size_t ws_size,
                              hipStream_t stream) {
  const float* x   = (const float*)d_in[0];
  const float* emb = (const float*)d_in[1];
  const float* W   = (const float*)d_in[2];
  const float* b   = (const float*)d_in[3];
  float* out = (float*)d_out;
  hipLaunchKernelGGL(daf_chain, dim3(Bn), dim3(64), 0, stream,
                     x, emb, W, b, out);
}

// Round 6
// 969.883 us; speedup vs baseline: 1.4808x; 1.4808x over previous
//
#include <hip/hip_runtime.h>
#include <cfloat>

// Problem constants (match reference)
constexpr int Bn = 1024, Ln = 1024, Vn = 20, Dn = 128;
constexpr int NJ = 2 * Vn;      // 40 output columns
constexpr int RESYNC = 16;      // exact f64 re-dot every RESYNC steps

// v mod 20 for 0 <= v <= ~1000 (magic multiply, exact in this range)
__device__ __forceinline__ int mod20(int v) { return v - 20 * ((v * 205) >> 12); }
__device__ __forceinline__ float max3f(float a, float b, float c) {
  return fmaxf(fmaxf(a, b), c);   // fuses to v_max3_f32
}
__device__ __forceinline__ unsigned min3u(unsigned a, unsigned b, unsigned c) {
  return min(min(a, b), c);       // fuses to v_min3_u32
}

// ---- X-macro lists over the 40 NAMED f32 nets ----
#define L40(M) M(0)M(1)M(2)M(3)M(4)M(5)M(6)M(7)M(8)M(9)M(10)M(11)M(12)M(13)M(14)M(15)M(16)M(17)M(18)M(19)M(20)M(21)M(22)M(23)M(24)M(25)M(26)M(27)M(28)M(29)M(30)M(31)M(32)M(33)M(34)M(35)M(36)M(37)M(38)M(39)
// float4 quads: (quad idx, n0..n3)
#define LQ(M) M(0,0,1,2,3)M(1,4,5,6,7)M(2,8,9,10,11)M(3,12,13,14,15)M(4,16,17,18,19)M(5,20,21,22,23)M(6,24,25,26,27)M(7,28,29,30,31)M(8,32,33,34,35)M(9,36,37,38,39)

__global__ __launch_bounds__(64, 1) void daf_chain(
    const float* __restrict__ x, const float* __restrict__ emb,
    const float* __restrict__ W, const float* __restrict__ bvec,
    float* __restrict__ out)
{
  __shared__ float  Ws[Dn * NJ];                 // 20480 B: W staged f32
  __shared__ float  embs[Vn * Dn];               // 10240 B
  __shared__ alignas(16) float EWf[Vn * NJ];     //  3200 B: EW[k][j] f32
  __shared__ alignas(16) double st64[Dn];        //  1024 B: f64 copy of f32 state
  __shared__ alignas(16) float nets40[NJ];       //   160 B: resync share buffer
  __shared__ unsigned char aidx[Ln];             //  1024 B: token index per step
  // total ~36 KB -> 4 blocks/CU

  const int lane  = threadIdx.x;
  const int batch = blockIdx.x;

  // Resync ownership: lanes 0..19 own loc columns, 32..51 own scale columns.
  const bool active = (lane < Vn) || (lane >= 32 && lane < 32 + Vn);
  const int  jm     = (lane < 32) ? lane : (lane - 32 + Vn);
  const int  jc     = active ? jm : 0;

  // ---- Prologue: stage W, emb; extract token indices (coalesced float4) ----
  for (int i = lane; i < Dn * NJ; i += 64) Ws[i] = W[i];
  for (int i = lane; i < Vn * Dn; i += 64) embs[i] = emb[i];
  const float4* xb4 = (const float4*)(x + (size_t)batch * Ln * Vn);
  for (int i = lane; i < Ln * (Vn / 4); i += 64) {  // 5 float4 per row of 20
    const float4 v = xb4[i];
    const int row = i / 5, cb = (i % 5) * 4;
    if (v.x > 0.5f) aidx[row] = (unsigned char)(cb + 0);
    if (v.y > 0.5f) aidx[row] = (unsigned char)(cb + 1);
    if (v.z > 0.5f) aidx[row] = (unsigned char)(cb + 2);
    if (v.w > 0.5f) aidx[row] = (unsigned char)(cb + 3);
  }
  __syncthreads();

  // ---- EW[k][j] = sum_d emb[k][d] * W[d][j] in f64, stored f32 ----
  for (int p = lane; p < Vn * NJ; p += 64) {
    const int k = p / NJ, j = p - k * NJ;
    double acc = 0.0;
#pragma unroll 4
    for (int d = 0; d < Dn; ++d)
      acc = __builtin_fma((double)embs[k * Dn + d], (double)Ws[d * NJ + j], acc);
    EWf[p] = (float)acc;
  }
  __syncthreads();

  const double bj = (double)bvec[jc];

  // All 40 nets replicated per lane, f32. Init = b exactly (state 0).
#define NINIT(i) float n##i = bvec[i];
  L40(NINIT)

  float s32a = 0.0f, s32b = 0.0f;   // bit-exact f32 state walk (d=lane, lane+64)
  float* outb = out + (size_t)batch * Ln * Vn;
  const double2* st2 = (const double2*)st64;
  const float*   Wsc = Ws + jc;

  for (int t = 0; t < Ln; ++t) {
    const int a = (int)aidx[t];     // uniform LDS read, independent -> early issue

    // ---- argmax half A (loc, j=0..19): max3 tree + first-max via min3 tree ----
    const float g0 = max3f(n0, n1, n2),   g1 = max3f(n3, n4, n5);
    const float g2 = max3f(n6, n7, n8),   g3 = max3f(n9, n10, n11);
    const float g4 = max3f(n12, n13, n14), g5 = max3f(n15, n16, n17);
    const float g6 = fmaxf(n18, n19);
    const float mxA = max3f(max3f(g0, g1, g2), max3f(g3, g4, g5), g6);
    unsigned iA;
    {
      const unsigned c0 = (n0 == mxA) ? 0u : 63u,  c1 = (n1 == mxA) ? 1u : 63u;
      const unsigned c2 = (n2 == mxA) ? 2u : 63u,  c3 = (n3 == mxA) ? 3u : 63u;
      const unsigned c4 = (n4 == mxA) ? 4u : 63u,  c5 = (n5 == mxA) ? 5u : 63u;
      const unsigned c6 = (n6 == mxA) ? 6u : 63u,  c7 = (n7 == mxA) ? 7u : 63u;
      const unsigned c8 = (n8 == mxA) ? 8u : 63u,  c9 = (n9 == mxA) ? 9u : 63u;
      const unsigned c10 = (n10 == mxA) ? 10u : 63u, c11 = (n11 == mxA) ? 11u : 63u;
      const unsigned c12 = (n12 == mxA) ? 12u : 63u, c13 = (n13 == mxA) ? 13u : 63u;
      const unsigned c14 = (n14 == mxA) ? 14u : 63u, c15 = (n15 == mxA) ? 15u : 63u;
      const unsigned c16 = (n16 == mxA) ? 16u : 63u, c17 = (n17 == mxA) ? 17u : 63u;
      const unsigned c18 = (n18 == mxA) ? 18u : 63u, c19 = (n19 == mxA) ? 19u : 63u;
      const unsigned h0 = min3u(c0, c1, c2),  h1 = min3u(c3, c4, c5);
      const unsigned h2 = min3u(c6, c7, c8),  h3 = min3u(c9, c10, c11);
      const unsigned h4 = min3u(c12, c13, c14), h5 = min3u(c15, c16, c17);
      const unsigned h6 = min(c18, c19);
      iA = min3u(min3u(h0, h1, h2), min3u(h3, h4, h5), h6);
    }
    // ---- argmax half B (scale, j=20..39) ----
    const float q0 = max3f(n20, n21, n22), q1 = max3f(n23, n24, n25);
    const float q2 = max3f(n26, n27, n28), q3 = max3f(n29, n30, n31);
    const float q4 = max3f(n32, n33, n34), q5 = max3f(n35, n36, n37);
    const float q6 = fmaxf(n38, n39);
    const float mxB = max3f(max3f(q0, q1, q2), max3f(q3, q4, q5), q6);
    unsigned iB;
    {
      const unsigned c0 = (n20 == mxB) ? 0u : 63u,  c1 = (n21 == mxB) ? 1u : 63u;
      const unsigned c2 = (n22 == mxB) ? 2u : 63u,  c3 = (n23 == mxB) ? 3u : 63u;
      const unsigned c4 = (n24 == mxB) ? 4u : 63u,  c5 = (n25 == mxB) ? 5u : 63u;
      const unsigned c6 = (n26 == mxB) ? 6u : 63u,  c7 = (n27 == mxB) ? 7u : 63u;
      const unsigned c8 = (n28 == mxB) ? 8u : 63u,  c9 = (n29 == mxB) ? 9u : 63u;
      const unsigned c10 = (n30 == mxB) ? 10u : 63u, c11 = (n31 == mxB) ? 11u : 63u;
      const unsigned c12 = (n32 == mxB) ? 12u : 63u, c13 = (n33 == mxB) ? 13u : 63u;
      const unsigned c14 = (n34 == mxB) ? 14u : 63u, c15 = (n35 == mxB) ? 15u : 63u;
      const unsigned c16 = (n36 == mxB) ? 16u : 63u, c17 = (n37 == mxB) ? 17u : 63u;
      const unsigned c18 = (n38 == mxB) ? 18u : 63u, c19 = (n39 == mxB) ? 19u : 63u;
      const unsigned h0 = min3u(c0, c1, c2),  h1 = min3u(c3, c4, c5);
      const unsigned h2 = min3u(c6, c7, c8),  h3 = min3u(c9, c10, c11);
      const unsigned h4 = min3u(c12, c13, c14), h5 = min3u(c15, c16, c17);
      const unsigned h6 = min(c18, c19);
      iB = min3u(min3u(h0, h1, h2), min3u(h3, h4, h5), h6);
    }

    const int loc   = __builtin_amdgcn_readfirstlane((int)iA);
    const int scale = __builtin_amdgcn_readfirstlane((int)iB);
    const int as    = __builtin_amdgcn_readfirstlane(a);

    // out_idx = (inv20(scale) * ((as - loc) mod 20)) mod 20   (scalar math)
    int r = as - loc; r += (r >> 31) & Vn;
    const int s  = scale;
    const int s2 = mod20(s * s);
    const int s4 = mod20(s2 * s2);
    const int s6 = mod20(s4 * s2);
    int inv = mod20(s6 * s);                 // s^7 mod 20 (= s^-1 for coprime s)
    const bool cop = ((s & 1) != 0) && ((s - 5 * ((s * 205) >> 10)) != 0);
    inv = cop ? inv : 0;                     // non-coprime -> INV_P row = e_0
    const int oidx = mod20(inv * r);

    // One-hot output row (80B store, fire-and-forget)
    if (lane < Vn) outb[(size_t)t * Vn + lane] = (lane == oidx) ? 1.0f : 0.0f;

    // Exact f32 state walk (bit-reproducible)
    s32a += embs[oidx * Dn + lane];
    s32b += embs[oidx * Dn + lane + 64];

    if (((t + 1) & (RESYNC - 1)) == 0 && (t + 1) < Ln) {
      // ---- Resync: nets = f32(b + f64 dot of exact f32 state). One column
      //      per lane, shared via 160B LDS broadcast. Resets f32 drift.
      st64[lane]      = (double)s32a;
      st64[lane + 64] = (double)s32b;
      double acc0 = 0.0, acc1 = 0.0, acc2 = 0.0, acc3 = 0.0;
#pragma unroll
      for (int d = 0; d < Dn; d += 4) {
        const double2 sA = st2[d >> 1];
        const double2 sB = st2[(d >> 1) + 1];
        acc0 = __builtin_fma(sA.x, (double)Wsc[(d + 0) * NJ], acc0);
        acc1 = __builtin_fma(sA.y, (double)Wsc[(d + 1) * NJ], acc1);
        acc2 = __builtin_fma(sB.x, (double)Wsc[(d + 2) * NJ], acc2);
        acc3 = __builtin_fma(sB.y, (double)Wsc[(d + 3) * NJ], acc3);
      }
      if (active) nets40[jm] = (float)(((acc0 + acc1) + (acc2 + acc3)) + bj);
      const float4* nr = (const float4*)nets40;
#define NLOAD(q, a_, b_, c_, d_) { const float4 v_ = nr[q]; \
      n##a_ = v_.x; n##b_ = v_.y; n##c_ = v_.z; n##d_ = v_.w; }
      LQ(NLOAD)
    } else {
      // ---- Incremental: nets += EW[oidx][:], 10 broadcast b128 reads ----
      const float4* er = (const float4*)(EWf + oidx * NJ);
#define NADD(q, a_, b_, c_, d_) { const float4 v_ = er[q]; \
      n##a_ += v_.x; n##b_ += v_.y; n##c_ += v_.z; n##d_ += v_.w; }
      LQ(NADD)
    }
  }
}

extern "C" void kernel_launch(void* const* d_in, const int* in_sizes, int n_in,
                              void* d_out, int out_size, void* d_ws, size_t ws_size,
                              hipStream_t stream) {
  const float* x   = (const float*)d_in[0];
  const float* emb = (const float*)d_in[1];
  const float* W   = (const float*)d_in[2];
  const float* b   = (const float*)d_in[3];
  float* out = (float*)d_out;
  hipLaunchKernelGGL(daf_chain, dim3(Bn), dim3(64), 0, stream,
                     x, emb, W, b, out);
}

// Round 7
// 361.802 us; speedup vs baseline: 3.9695x; 2.6807x over previous
//
#include <hip/hip_runtime.h>
#include <cfloat>

// Problem constants (match reference)
constexpr int Bn = 1024, Ln = 1024, Vn = 20, Dn = 128;
constexpr int NJ = 2 * Vn;      // 40 output columns
constexpr int TB = 16;          // steps per resync block

// v mod 20 for 0 <= v <= ~4000 (magic multiply, exact in this range)
__device__ __forceinline__ int mod20(int v) { return v - 20 * ((v * 205) >> 12); }

// ---- DPP helpers: in-row (16-lane) butterfly reduce, pure VALU ----
template<int CTRL>
__device__ __forceinline__ float dpp_max(float v) {
  const int s = __builtin_amdgcn_update_dpp(0, __float_as_int(v), CTRL, 0xF, 0xF, false);
  return fmaxf(v, __int_as_float(s));
}
template<int CTRL>
__device__ __forceinline__ unsigned dpp_min(unsigned v) {
  const unsigned s =
      (unsigned)__builtin_amdgcn_update_dpp(0, (int)v, CTRL, 0xF, 0xF, false);
  return v < s ? v : s;
}
__device__ __forceinline__ float rowmax16(float v) {
  v = dpp_max<0xB1>(v);    // quad_perm [1,0,3,2]  (xor 1)
  v = dpp_max<0x4E>(v);    // quad_perm [2,3,0,1]  (xor 2)
  v = dpp_max<0x141>(v);   // row_half_mirror      (pairs across 4-groups)
  v = dpp_max<0x140>(v);   // row_mirror           (pairs across 8-groups)
  return v;
}
__device__ __forceinline__ unsigned rowmin16(unsigned v) {
  v = dpp_min<0xB1>(v);
  v = dpp_min<0x4E>(v);
  v = dpp_min<0x141>(v);
  v = dpp_min<0x140>(v);
  return v;
}

// inv mod 20 packed table: 5-bit entries for odd s, indexed by s>>1
constexpr unsigned long long INVT =
    (1ull << 0) | (7ull << 5) | (0ull << 10) | (3ull << 15) | (9ull << 20) |
    (11ull << 25) | (17ull << 30) | (0ull << 35) | (13ull << 40) | (19ull << 45);

__global__ __launch_bounds__(64, 1) void daf_chain(
    const float* __restrict__ x, const float* __restrict__ emb,
    const float* __restrict__ W, const float* __restrict__ bvec,
    float* __restrict__ out)
{
  __shared__ float Ws[Dn * NJ];                  // 20480 B: W row-major f32
  __shared__ float embd[Vn * Dn];                // 10240 B: emb rows f32
  __shared__ alignas(8) float ewd2[Vn * 64];     //  5120 B: EW distributed {lo,hi}/pos
  __shared__ alignas(16) double st64[Dn];        //  1024 B: f64 copy of f32 state
  __shared__ float nets40[64];                   //   256 B: resync share (padded)
  __shared__ unsigned char aidx[Ln];             //  1024 B: token index per step
  // total 38144 B -> 4 blocks/CU (152 KiB of 160)

  const int lane = threadIdx.x;
  const int batch = blockIdx.x;
  const int p   = lane & 15;          // position within row
  const int rB  = (lane >> 4) & 1;    // 0 = loc group row, 1 = scale group row
  const int pos = lane & 31;          // row-pair position (lanes 32..63 mirror)

  // resync column ownership (40 owner lanes, R6 mapping)
  const bool own = (lane < Vn) || (lane >= 32 && lane < 32 + Vn);
  const int  jm  = (lane < 32) ? lane : (lane - 32 + Vn);
  const int  jc  = own ? jm : 0;

  // ---- Prologue: stage W, emb; extract token indices (coalesced float4) ----
  for (int i = lane; i < Dn * NJ; i += 64) Ws[i] = W[i];
  for (int i = lane; i < Vn * Dn; i += 64) embd[i] = emb[i];
  const float4* xb4 = (const float4*)(x + (size_t)batch * Ln * Vn);
  for (int i = lane; i < Ln * (Vn / 4); i += 64) {
    const float4 v = xb4[i];
    const int row = i / 5, cb = (i % 5) * 4;
    if (v.x > 0.5f) aidx[row] = (unsigned char)(cb + 0);
    if (v.y > 0.5f) aidx[row] = (unsigned char)(cb + 1);
    if (v.z > 0.5f) aidx[row] = (unsigned char)(cb + 2);
    if (v.w > 0.5f) aidx[row] = (unsigned char)(cb + 3);
  }
  __syncthreads();

  // ---- EW[k][j] = f64 dot(emb[k], W[:,j]) -> f32, stored distributed ----
  // layout: ewd2[k*64 + q*2 + slot]; row0 q<16: lo j=q, hi j=16+q (q<4)
  //         row1 q>=16: lo j=20+(q-16), hi j=36+(q-16) (q-16<4)
  for (int e = lane; e < Vn * NJ; e += 64) {
    const int k = e / NJ, j = e - k * NJ;
    double acc = 0.0;
#pragma unroll 4
    for (int d = 0; d < Dn; ++d)
      acc = __builtin_fma((double)embd[k * Dn + d], (double)Ws[d * NJ + j], acc);
    int q, slot;
    if (j < 16)      { q = j;             slot = 0; }
    else if (j < 20) { q = j - 16;        slot = 1; }
    else if (j < 36) { q = 16 + (j - 20); slot = 0; }
    else             { q = 16 + (j - 36); slot = 1; }
    ewd2[k * 64 + q * 2 + slot] = (float)acc;
  }
  // zero undefined hi slots so (-inf += 0) stays -inf
  if ((pos & 15) >= 4)
    for (int k = 0; k < Vn; ++k) ewd2[k * 64 + pos * 2 + 1] = 0.0f;
  __syncthreads();

  // ---- init nets (distributed): exact f32 b (state 0) ----
  const int jlo = rB ? (20 + p) : p;
  float nlo = bvec[jlo];
  float nhi = (p < 4) ? bvec[jlo + 16] : -FLT_MAX;
  const double bj = (double)bvec[jc];

  float s32a = 0.0f, s32b = 0.0f;   // bit-exact f32 state walk (d=lane, lane+64)
  float* outb = out + (size_t)batch * Ln * Vn;
  const double2* st2 = (const double2*)st64;
  const float*   Wsc = Ws + jc;
  const float2*  ew2 = (const float2*)ewd2;

  auto STEP = [&](int t, bool doAdd) {
    const int tokv = (int)aidx[t];              // uniform, off-chain

    // argmax both groups simultaneously: local pair max, 4-step DPP butterfly
    float m = fmaxf(nlo, nhi);
    m = rowmax16(m);
    // first-max index: prefer lo (smaller j), then min-reduce across row
    unsigned cand = (nlo == m) ? (unsigned)p
                               : ((nhi == m) ? (unsigned)(p + 16) : 63u);
    cand = rowmin16(cand);

    const int locI = __builtin_amdgcn_readlane((int)cand, 0);   // row0 result
    const int sclI = __builtin_amdgcn_readlane((int)cand, 16);  // row1 result
    const int as   = __builtin_amdgcn_readfirstlane(tokv);

    // oidx = (inv20(scale) * ((a - loc) mod 20)) mod 20  (scalar chain)
    int r = as - locI; r += (r >> 31) & Vn;
    const int inv = (sclI & 1) ? (int)((INVT >> ((sclI >> 1) * 5)) & 31ull) : 0;
    const int oidx = mod20(inv * r);

    // one-hot output row (80 B store, fire-and-forget)
    if (lane < Vn) outb[(size_t)t * Vn + lane] = (lane == oidx) ? 1.0f : 0.0f;

    // exact f32 state walk
    s32a += embd[oidx * Dn + lane];
    s32b += embd[oidx * Dn + lane + 64];

    if (doAdd) {                                 // incremental net update
      const float2 e = ew2[oidx * 32 + pos];
      nlo += e.x; nhi += e.y;
    }
  };

  auto RESYNC = [&]() {
    // nets = f32(b + f64 dot of exact f32 state) — proven numerics (R4-R6)
    st64[lane]      = (double)s32a;
    st64[lane + 64] = (double)s32b;
    __syncthreads();
    double a0 = 0.0, a1 = 0.0, a2 = 0.0, a3 = 0.0;
#pragma unroll
    for (int d = 0; d < Dn; d += 4) {
      const double2 sA = st2[d >> 1];
      const double2 sB = st2[(d >> 1) + 1];
      a0 = __builtin_fma(sA.x, (double)Wsc[(d + 0) * NJ], a0);
      a1 = __builtin_fma(sA.y, (double)Wsc[(d + 1) * NJ], a1);
      a2 = __builtin_fma(sB.x, (double)Wsc[(d + 2) * NJ], a2);
      a3 = __builtin_fma(sB.y, (double)Wsc[(d + 3) * NJ], a3);
    }
    if (own) nets40[jm] = (float)(((a0 + a1) + (a2 + a3)) + bj);
    __syncthreads();
    nlo = nets40[rB * 20 + p];
    nhi = (p < 4) ? nets40[rB * 20 + 16 + p] : -FLT_MAX;
  };

  for (int tb = 0; tb < Ln / TB; ++tb) {
#pragma unroll
    for (int u = 0; u < TB; ++u) STEP(tb * TB + u, u != TB - 1);
    if (tb != Ln / TB - 1) RESYNC();
  }
}

extern "C" void kernel_launch(void* const* d_in, const int* in_sizes, int n_in,
                              void* d_out, int out_size, void* d_ws, size_t ws_size,
                              hipStream_t stream) {
  const float* x   = (const float*)d_in[0];
  const float* emb = (const float*)d_in[1];
  const float* W   = (const float*)d_in[2];
  const float* b   = (const float*)d_in[3];
  float* out = (float*)d_out;
  hipLaunchKernelGGL(daf_chain, dim3(Bn), dim3(64), 0, stream,
                     x, emb, W, b, out);
}